// Round 5
// baseline (972.435 us; speedup 1.0000x reference)
//
#include <hip/hip_runtime.h>
#include <hip/hip_bf16.h>
#include <math.h>

// Problem constants. Device dtypes: all 12 inputs fp32, OUTPUT fp32.
#define BB 4
#define SS 4096
#define HH 8
#define DI 128
#define DOo 128
#define HD 1024        // HH*DI
#define NTOK (BB*SS)   // 16384
#define LNEPS 1e-6f

// cumsum chunking
#define CS1 64
#define NC1 64         // SS/CS1
// recurrence chunking
#define CS2 128
#define NC2 32         // SS/CS2

typedef __hip_bfloat16 bf16;

__device__ __forceinline__ float b2f(bf16 x) { return __bfloat162float(x); }
__device__ __forceinline__ bf16 f2b(float x) { return __float2bfloat16(x); }

// ---------------- block-wide reduction of two floats over blockDim.x (multiple of 64, <=1024)
__device__ __forceinline__ void blockReduce2(float& a, float& b, float2* scratch) {
    __syncthreads();  // protect scratch reuse when called in a loop
    int lane = threadIdx.x & 63;
    int wid  = threadIdx.x >> 6;
    #pragma unroll
    for (int off = 32; off > 0; off >>= 1) {
        a += __shfl_down(a, off);
        b += __shfl_down(b, off);
    }
    if (lane == 0) scratch[wid] = make_float2(a, b);
    __syncthreads();
    int nw = blockDim.x >> 6;
    if (wid == 0) {
        float2 v = (lane < nw) ? scratch[lane] : make_float2(0.f, 0.f);
        a = v.x; b = v.y;
        #pragma unroll
        for (int off = 8; off > 0; off >>= 1) {  // up to 16 waves
            a += __shfl_down(a, off);
            b += __shfl_down(b, off);
        }
        if (lane == 0) scratch[0] = make_float2(a, b);
    }
    __syncthreads();
    float2 r = scratch[0];
    a = r.x; b = r.y;
}

// ---------------- KW: fp32 -> bf16 weight conversion (grid-stride)
__global__ void kw_cvt(const float* __restrict__ a, bf16* __restrict__ o, int n) {
    for (int i = blockIdx.x * blockDim.x + threadIdx.x; i < n; i += gridDim.x * blockDim.x)
        o[i] = f2b(a[i]);
}

// ---------------- K1: per-chunk sums along S for the cumsum
__global__ void k1_chunksum(const float* __restrict__ in, float* __restrict__ chunk) {
    int bid = blockIdx.x;                 // b*HH*NC1 + h*NC1 + c
    int c = bid % NC1;
    int h = (bid / NC1) % HH;
    int b = bid / (NC1 * HH);
    int d = threadIdx.x;                  // 0..127
    const float* p = in + (size_t)(b * SS + c * CS1) * HD + h * DI + d;
    float s = 0.f;
    for (int i = 0; i < CS1; ++i) s += p[(size_t)i * HD];
    chunk[((b * NC1 + c) * HH + h) * DI + d] = s;
}

// ---------------- K2: serial exclusive scan over chunks (in-place)
__global__ void k2_chunkscan(float* __restrict__ chunk) {
    int bid = blockIdx.x;                 // b*HH + h
    int h = bid % HH;
    int b = bid / HH;
    int d = threadIdx.x;
    float run = 0.f;
    for (int c = 0; c < NC1; ++c) {
        int idx = ((b * NC1 + c) * HH + h) * DI + d;
        float v = chunk[idx];
        chunk[idx] = run;
        run += v;
    }
}

// ---------------- K3: in-chunk exclusive cumsum + LayerNorm over (H,DI)=1024 per token
// Writes csln (fp32) into D_OUT — consumed (and then overwritten in-place) by k4_fused.
__global__ void __launch_bounds__(1024) k3_csum_ln(
        const float* __restrict__ in, const float* __restrict__ chunkpre,
        const float* __restrict__ g, const float* __restrict__ beta,
        float* __restrict__ out) {
    __shared__ float2 scratch[16];
    int c = blockIdx.x % NC1;
    int b = blockIdx.x / NC1;
    int t = threadIdx.x;                  // h*DI + d, 0..1023
    float run = chunkpre[(b * NC1 + c) * HD + t];
    const float* pin = in + (size_t)(b * SS + c * CS1) * HD + t;
    float* pout = out + (size_t)(b * SS + c * CS1) * HD + t;
    float gg = g[t], bb = beta[t];
    for (int i = 0; i < CS1; ++i) {
        float v = pin[(size_t)i * HD];
        float cs = run;
        run += v;
        float a = cs, b2 = cs * cs;
        blockReduce2(a, b2, scratch);
        float mu  = a * (1.f / 1024.f);
        float var = b2 * (1.f / 1024.f) - mu * mu;
        float r = rsqrtf(var + LNEPS);
        pout[(size_t)i * HD] = (cs - mu) * r * gg + bb;
    }
}

// ---------------- K4 fused: per-token GEMM (all heads) + LN over 3072 + gates.
// One block owns T4=8 tokens. Stages x=[in, csln] for its tokens into LDS, then
// overwrites its own tokens' csln region (d_out) with igh. fgl (forget logit) -> ws.
#define T4 8
__global__ void __launch_bounds__(1024) k4_fused(
        const float* __restrict__ in, float* __restrict__ dout /* csln in, igh out */,
        const bf16* __restrict__ Wb, const float* __restrict__ bias,
        const float* __restrict__ g, const float* __restrict__ beta,
        float* __restrict__ fgl) {
    __shared__ float xs[T4][2048];        // 64 KiB
    __shared__ float2 scratch[16];
    int tok0 = blockIdx.x * T4;
    int t = threadIdx.x;                  // 0..1023
    // stage x = [in(0..127), csln(0..127)] per head
    for (int i = t; i < T4 * 2048; i += 1024) {
        int tt = i >> 11, r = i & 2047, hh = r >> 8, k = r & 255;
        size_t base = (size_t)(tok0 + tt) * HD + hh * DI;
        xs[tt][r] = (k < 128) ? in[base + k] : dout[base + (k - 128)];
    }
    __syncthreads();
    int h = t >> 7, dim = t & 127;
    const bf16* wp = Wb + (size_t)h * 256 * 384;
    float b0 = bias[h * 384 + dim];
    float b1 = bias[h * 384 + 128 + dim];
    float b2c = bias[h * 384 + 256 + dim];
    float acc[T4][3];
    #pragma unroll
    for (int tt = 0; tt < T4; ++tt) { acc[tt][0] = 0.f; acc[tt][1] = 0.f; acc[tt][2] = 0.f; }
    for (int k = 0; k < 256; ++k) {
        float w0 = b2f(wp[k * 384 + dim]);
        float w1 = b2f(wp[k * 384 + 128 + dim]);
        float w2 = b2f(wp[k * 384 + 256 + dim]);
        #pragma unroll
        for (int tt = 0; tt < T4; ++tt) {
            float x = xs[tt][h * 256 + k];    // LDS broadcast within each head group
            acc[tt][0] += x * w0;
            acc[tt][1] += x * w1;
            acc[tt][2] += x * w2;
        }
    }
    float gi = g[(h * 3 + 0) * 128 + dim], bi = beta[(h * 3 + 0) * 128 + dim];
    float gf = g[(h * 3 + 1) * 128 + dim], bff = beta[(h * 3 + 1) * 128 + dim];
    float gh = g[(h * 3 + 2) * 128 + dim], bh = beta[(h * 3 + 2) * 128 + dim];
    for (int tt = 0; tt < T4; ++tt) {
        float vi = acc[tt][0] + b0;
        float vf = acc[tt][1] + b1;
        float vh = acc[tt][2] + b2c;
        float a = vi + vf + vh;
        float sq = vi * vi + vf * vf + vh * vh;
        blockReduce2(a, sq, scratch);             // over 3072 values of this token
        float mu  = a * (1.f / 3072.f);
        float var = sq * (1.f / 3072.f) - mu * mu;
        float r = rsqrtf(var + LNEPS);
        float li = (vi - mu) * r * gi + bi;
        float lf = (vf - mu) * r * gf + bff;
        float lh = (vh - mu) * r * gh + bh;
        size_t o = (size_t)(tok0 + tt) * HD + t;
        fgl[o]  = lf;                                              // forget-gate LOGIT
        dout[o] = (1.f / (1.f + expf(-li))) * fmaxf(lh, 0.f);      // igh, in-place over csln
    }
}

// ---------------- K5a: per-chunk recurrence summary: P = prod f, L = local end value
__global__ void k5a_chunkrec(const float* __restrict__ fgl, const float* __restrict__ igh,
                             float* __restrict__ Pb, float* __restrict__ Lb) {
    int bid = blockIdx.x;                 // b*NC2*HH + c*HH + h
    int h = bid % HH;
    int c = (bid / HH) % NC2;
    int b = bid / (HH * NC2);
    int d = threadIdx.x;
    size_t base = (size_t)(b * SS + c * CS2) * HD + h * DOo + d;
    float P = 1.f, L = 0.f;
    for (int s = 0; s < CS2; ++s) {
        float f = 1.f / (1.f + expf(-fgl[base + (size_t)s * HD]));
        float i = igh[base + (size_t)s * HD];
        L = f * L + i;
        P *= f;
    }
    int o = ((b * NC2 + c) * HH + h) * DOo + d;
    Pb[o] = P;
    Lb[o] = L;
}

// ---------------- K5b: serial carry across chunks
__global__ void k5b_carry(const float* __restrict__ Pb, const float* __restrict__ Lb,
                          const float* __restrict__ init_cx, float* __restrict__ cIn) {
    int bid = blockIdx.x;                 // b*HH + h
    int h = bid % HH;
    int b = bid / HH;
    int d = threadIdx.x;
    float c = init_cx[h * DOo + d];
    for (int cc = 0; cc < NC2; ++cc) {
        int o = ((b * NC2 + cc) * HH + h) * DOo + d;
        cIn[o] = c;
        c = Pb[o] * c + Lb[o];
    }
}

// ---------------- K5c: final in-chunk recurrence, writes cell in place of igh (d_out)
__global__ void k5c_cell(const float* __restrict__ fgl, float* __restrict__ igh_cell,
                         const float* __restrict__ cIn) {
    int bid = blockIdx.x;
    int h = bid % HH;
    int c = (bid / HH) % NC2;
    int b = bid / (HH * NC2);
    int d = threadIdx.x;
    size_t base = (size_t)(b * SS + c * CS2) * HD + h * DOo + d;
    int o = ((b * NC2 + c) * HH + h) * DOo + d;
    float cv = cIn[o];
    for (int s = 0; s < CS2; ++s) {
        float f = 1.f / (1.f + expf(-fgl[base + (size_t)s * HD]));
        float i = igh_cell[base + (size_t)s * HD];
        cv = f * cv + i;
        igh_cell[base + (size_t)s * HD] = cv;
    }
}

// ---------------- K6: og GEMM + LN over (H,DO)=1024 per token + sigmoid*cell -> out
// (in place over cell; each block owns its tokens, stages cell to LDS first)
#define TT6 4
__global__ void __launch_bounds__(1024) k6_out(
        const float* __restrict__ in, float* __restrict__ cell_out,
        const bf16* __restrict__ Wb, const float* __restrict__ bias,
        const float* __restrict__ g, const float* __restrict__ beta) {
    __shared__ float xs[TT6][2048];       // 32 KiB
    __shared__ float2 scratch[16];
    int tok0 = blockIdx.x * TT6;
    int t = threadIdx.x;                  // 0..1023
    int h = t >> 7, j = t & 127;
    for (int i = t; i < TT6 * 2048; i += 1024) {
        int tt = i >> 11;
        int r = i & 2047;
        int hh = r >> 8, k = r & 255;
        size_t base = (size_t)(tok0 + tt) * HD + hh * DI;
        xs[tt][r] = (k < 128) ? in[base + k] : cell_out[base + (k - 128)];
    }
    __syncthreads();
    float acc[TT6];
    #pragma unroll
    for (int tt = 0; tt < TT6; ++tt) acc[tt] = 0.f;
    const bf16* wp = Wb + (size_t)h * 256 * 128 + j;
    for (int k = 0; k < 256; ++k) {
        float w = b2f(wp[(size_t)k * 128]);
        #pragma unroll
        for (int tt = 0; tt < TT6; ++tt) acc[tt] += xs[tt][h * 256 + k] * w;
    }
    float bb = bias[h * DOo + j], gg = g[h * DOo + j], be = beta[h * DOo + j];
    for (int tt = 0; tt < TT6; ++tt) {
        float v = acc[tt] + bb;
        float a = v, b2 = v * v;
        blockReduce2(a, b2, scratch);
        float mu  = a * (1.f / 1024.f);
        float var = b2 * (1.f / 1024.f) - mu * mu;
        float r = rsqrtf(var + LNEPS);
        float og = (v - mu) * r * gg + be;
        float cv = xs[tt][h * 256 + 128 + j];
        cell_out[(size_t)(tok0 + tt) * HD + t] = (1.f / (1.f + expf(-og))) * cv;
    }
}

extern "C" void kernel_launch(void* const* d_in, const int* in_sizes, int n_in,
                              void* d_out, int out_size, void* d_ws, size_t ws_size,
                              hipStream_t stream) {
    const float* heads_input = (const float*)d_in[0];
    const float* W_hid   = (const float*)d_in[1];
    const float* b_hid   = (const float*)d_in[2];
    const float* g_csum  = (const float*)d_in[3];
    const float* beta_csum = (const float*)d_in[4];
    const float* g_hid   = (const float*)d_in[5];
    const float* beta_hid = (const float*)d_in[6];
    const float* W_og    = (const float*)d_in[7];
    const float* b_og    = (const float*)d_in[8];
    const float* g_og    = (const float*)d_in[9];
    const float* beta_og = (const float*)d_in[10];
    const float* init_cx = (const float*)d_in[11];
    float* out = (float*)d_out;           // fp32 output, NTOK*HD elements

    // workspace layout (~72 MB total)
    char* ws = (char*)d_ws;
    float* fgl   = (float*)ws;                                 // 67,108,864 B
    float* chunk = fgl + (size_t)NTOK * HD;                    //  1,048,576 B
    float* Pb    = chunk + (size_t)BB * NC1 * HD;              //    524,288 B
    float* Lb    = Pb + (size_t)BB * NC2 * HD;                 //    524,288 B
    float* cIn   = Lb + (size_t)BB * NC2 * HD;                 //    524,288 B
    bf16* Wb_hid = (bf16*)(cIn + (size_t)BB * NC2 * HD);       //  1,572,864 B
    bf16* Wb_og  = Wb_hid + (size_t)HH * 256 * 384;            //    524,288 B

    kw_cvt<<<512, 256, 0, stream>>>(W_hid, Wb_hid, HH * 256 * 384);
    kw_cvt<<<256, 256, 0, stream>>>(W_og, Wb_og, HH * 256 * 128);
    k1_chunksum<<<BB * HH * NC1, 128, 0, stream>>>(heads_input, chunk);
    k2_chunkscan<<<BB * HH, 128, 0, stream>>>(chunk);
    k3_csum_ln<<<BB * NC1, 1024, 0, stream>>>(heads_input, chunk, g_csum, beta_csum, out);
    k4_fused<<<NTOK / T4, 1024, 0, stream>>>(heads_input, out, Wb_hid, b_hid, g_hid, beta_hid, fgl);
    k5a_chunkrec<<<BB * NC2 * HH, 128, 0, stream>>>(fgl, out, Pb, Lb);
    k5b_carry<<<BB * HH, 128, 0, stream>>>(Pb, Lb, init_cx, cIn);
    k5c_cell<<<BB * NC2 * HH, 128, 0, stream>>>(fgl, out, cIn);
    k6_out<<<NTOK / TT6, 1024, 0, stream>>>(heads_input, out, Wb_og, b_og, g_og, beta_og);
}

// Round 6
// 540.061 us; speedup vs baseline: 1.8006x; 1.8006x over previous
//
#include <hip/hip_runtime.h>
#include <math.h>

// Problem constants. Device dtypes: all 12 inputs fp32, OUTPUT fp32.
#define BB 4
#define SS 4096
#define HH 8
#define DI 128
#define DOo 128
#define HD 1024        // HH*DI
#define NTOK (BB*SS)   // 16384
#define LNEPS 1e-6f

// cumsum chunking
#define CS1 64
#define NC1 64         // SS/CS1
// recurrence chunking
#define CS2 128
#define NC2 32         // SS/CS2

typedef unsigned short ubf;   // bf16 bits
typedef __attribute__((ext_vector_type(8))) short    bf16x8;
typedef __attribute__((ext_vector_type(8))) unsigned short u16x8;
typedef __attribute__((ext_vector_type(4))) unsigned short u16x4;
typedef __attribute__((ext_vector_type(4))) float    f32x4;

__device__ __forceinline__ float bf2f(ubf x) {
    union { unsigned int u; float f; } v; v.u = ((unsigned int)x) << 16; return v.f;
}
__device__ __forceinline__ ubf f2bf(float f) {
    union { float f; unsigned int u; } v; v.f = f;
    unsigned int r = v.u + 0x7FFFu + ((v.u >> 16) & 1u);   // RNE
    return (ubf)(r >> 16);
}

// ---------------- block-wide reduction of two floats over blockDim.x (multiple of 64, <=1024)
__device__ __forceinline__ void blockReduce2(float& a, float& b, float2* scratch) {
    __syncthreads();
    int lane = threadIdx.x & 63;
    int wid  = threadIdx.x >> 6;
    #pragma unroll
    for (int off = 32; off > 0; off >>= 1) {
        a += __shfl_down(a, off);
        b += __shfl_down(b, off);
    }
    if (lane == 0) scratch[wid] = make_float2(a, b);
    __syncthreads();
    int nw = blockDim.x >> 6;
    if (wid == 0) {
        float2 v = (lane < nw) ? scratch[lane] : make_float2(0.f, 0.f);
        a = v.x; b = v.y;
        #pragma unroll
        for (int off = 8; off > 0; off >>= 1) {
            a += __shfl_down(a, off);
            b += __shfl_down(b, off);
        }
        if (lane == 0) scratch[0] = make_float2(a, b);
    }
    __syncthreads();
    float2 r = scratch[0];
    a = r.x; b = r.y;
}

// ---------------- KWT: W[h][256][NB] fp32 -> Wt[h][NB][256] bf16 (transpose for k-contiguous frags)
__global__ void kwt(const float* __restrict__ W, ubf* __restrict__ Wt, int NB) {
    int b = blockIdx.x;           // h*NB + n
    int h = b / NB, n = b % NB;
    int k = threadIdx.x;          // 0..255
    Wt[((size_t)h * NB + n) * 256 + k] = f2bf(W[((size_t)h * 256 + k) * NB + n]);
}

// ---------------- K1: per-chunk sums along S for the cumsum + emit in as bf16
__global__ void k1_chunksum(const float* __restrict__ in, float* __restrict__ chunk,
                            ubf* __restrict__ in_bf) {
    int bid = blockIdx.x;                 // b*HH*NC1 + h*NC1 + c
    int c = bid % NC1;
    int h = (bid / NC1) % HH;
    int b = bid / (NC1 * HH);
    int d = threadIdx.x;                  // 0..127
    size_t base = (size_t)(b * SS + c * CS1) * HD + h * DI + d;
    float s = 0.f;
    for (int i = 0; i < CS1; ++i) {
        float v = in[base + (size_t)i * HD];
        in_bf[base + (size_t)i * HD] = f2bf(v);
        s += v;
    }
    chunk[((b * NC1 + c) * HH + h) * DI + d] = s;
}

// ---------------- K2: serial exclusive scan over chunks (in-place)
__global__ void k2_chunkscan(float* __restrict__ chunk) {
    int bid = blockIdx.x;                 // b*HH + h
    int h = bid % HH;
    int b = bid / HH;
    int d = threadIdx.x;
    float run = 0.f;
    for (int c = 0; c < NC1; ++c) {
        int idx = ((b * NC1 + c) * HH + h) * DI + d;
        float v = chunk[idx];
        chunk[idx] = run;
        run += v;
    }
}

// ---------------- K3: in-chunk exclusive cumsum + LayerNorm over (H,DI)=1024 per token -> csln bf16
__global__ void __launch_bounds__(1024) k3_csum_ln(
        const float* __restrict__ in, const float* __restrict__ chunkpre,
        const float* __restrict__ g, const float* __restrict__ beta,
        ubf* __restrict__ out) {
    __shared__ float2 scratch[16];
    int c = blockIdx.x % NC1;
    int b = blockIdx.x / NC1;
    int t = threadIdx.x;                  // h*DI + d, 0..1023
    float run = chunkpre[(b * NC1 + c) * HD + t];
    const float* pin = in + (size_t)(b * SS + c * CS1) * HD + t;
    ubf* pout = out + (size_t)(b * SS + c * CS1) * HD + t;
    float gg = g[t], bb = beta[t];
    for (int i = 0; i < CS1; ++i) {
        float v = pin[(size_t)i * HD];
        float cs = run;
        run += v;
        float a = cs, b2 = cs * cs;
        blockReduce2(a, b2, scratch);
        float mu  = a * (1.f / 1024.f);
        float var = b2 * (1.f / 1024.f) - mu * mu;
        float r = rsqrtf(var + LNEPS);
        pout[(size_t)i * HD] = f2bf((cs - mu) * r * gg + bb);
    }
}

// ---------------- GEMM (MFMA): per-head C[tok][h*NB+n] = [Ab0_h | Ab1_h](tok, 256) @ Wt[h]^T
// Ab0/Ab1: [NTOK][1024] bf16, head slice at h*128, each 128 wide (k<128 / k>=128).
// Wt: [H][NB][256] bf16 (n-major, k-contiguous). C: [NTOK][H*NB] bf16 (no bias).
// BM=128, BN=128, BK=32; 256 threads = 4 waves; wave = 64x64 via 4x4 mfma_16x16x32.
__global__ void __launch_bounds__(256) gemm_h(
        const ubf* __restrict__ Ab0, const ubf* __restrict__ Ab1,
        const ubf* __restrict__ Wt, ubf* __restrict__ C, int NB) {
    __shared__ __align__(16) ubf As[128 * 32];   // fragment-packed: ((mt*64 + kq*16 + mr)*8 + kj)
    __shared__ __align__(16) ubf Bs[128 * 32];
    int tok0 = blockIdx.x * 128;
    int h = blockIdx.y;
    int n0 = blockIdx.z * 128;
    int t = threadIdx.x;
    int lane = t & 63, w = t >> 6;
    int crs = NB * HH;                    // C row stride

    f32x4 acc[4][4];
    #pragma unroll
    for (int i = 0; i < 4; ++i)
        #pragma unroll
        for (int j = 0; j < 4; ++j) acc[i][j] = (f32x4){0.f, 0.f, 0.f, 0.f};

    for (int ks = 0; ks < 8; ++ks) {
        int k0 = ks * 32;
        const ubf* Asrc = (k0 < 128) ? Ab0 : Ab1;
        int kk = k0 & 127;
        __syncthreads();
        // stage A: 128 rows x 32 k = 512 x b128
        #pragma unroll
        for (int it = 0; it < 2; ++it) {
            int slot = it * 256 + t;
            int row = slot >> 2, kq = slot & 3;
            u16x8 v = *(const u16x8*)(Asrc + (size_t)(tok0 + row) * HD + h * DI + kk + kq * 8);
            *(u16x8*)(As + ((row >> 4) * 64 + kq * 16 + (row & 15)) * 8) = v;
        }
        // stage B: 128 n-rows x 32 k
        #pragma unroll
        for (int it = 0; it < 2; ++it) {
            int slot = it * 256 + t;
            int nrow = slot >> 2, kq = slot & 3;
            u16x8 v = *(const u16x8*)(Wt + ((size_t)h * NB + n0 + nrow) * 256 + k0 + kq * 8);
            *(u16x8*)(Bs + ((nrow >> 4) * 64 + kq * 16 + (nrow & 15)) * 8) = v;
        }
        __syncthreads();
        int mb = (w & 1) * 4, nb = (w >> 1) * 4;
        bf16x8 af[4], bfr[4];
        #pragma unroll
        for (int i = 0; i < 4; ++i) af[i]  = *(const bf16x8*)(As + ((mb + i) * 64 + lane) * 8);
        #pragma unroll
        for (int i = 0; i < 4; ++i) bfr[i] = *(const bf16x8*)(Bs + ((nb + i) * 64 + lane) * 8);
        #pragma unroll
        for (int i = 0; i < 4; ++i)
            #pragma unroll
            for (int j = 0; j < 4; ++j)
                acc[i][j] = __builtin_amdgcn_mfma_f32_16x16x32_bf16(af[i], bfr[j], acc[i][j], 0, 0, 0);
    }
    // epilogue: C/D layout col=lane&15, row=quad*4+reg  (m89/m91-verified)
    int mbase = tok0 + (w & 1) * 64 + (lane >> 4) * 4;
    int nbase = h * NB + n0 + (w >> 1) * 64 + (lane & 15);
    #pragma unroll
    for (int i = 0; i < 4; ++i)
        #pragma unroll
        for (int j = 0; j < 4; ++j) {
            #pragma unroll
            for (int r = 0; r < 4; ++r)
                C[(size_t)(mbase + i * 16 + r) * crs + nbase + j * 16] = f2bf(acc[i][j][r]);
        }
}

// ---------------- K4b: +bias, LN over (H,3,DO)=3072 per token, gates.
// fgl = forget LOGIT bf16 (ws); igh = sigmoid(i)*relu(h) fp32 -> d_out.
__global__ void __launch_bounds__(1024) k4b_ln_gates(
        const ubf* __restrict__ h3, const float* __restrict__ bias,
        const float* __restrict__ g, const float* __restrict__ beta,
        ubf* __restrict__ fgl, float* __restrict__ igh) {
    __shared__ float2 scratch[16];
    size_t base = (size_t)blockIdx.x * 3072;
    int t = threadIdx.x;
    int h = t >> 7, j = t & 127;
    float vi = bf2f(h3[base + h * 384 + j])       + bias[h * 384 + j];
    float vf = bf2f(h3[base + h * 384 + 128 + j]) + bias[h * 384 + 128 + j];
    float vh = bf2f(h3[base + h * 384 + 256 + j]) + bias[h * 384 + 256 + j];
    float a = vi + vf + vh;
    float sq = vi * vi + vf * vf + vh * vh;
    blockReduce2(a, sq, scratch);
    float mu  = a * (1.f / 3072.f);
    float var = sq * (1.f / 3072.f) - mu * mu;
    float r = rsqrtf(var + LNEPS);
    int gi = (h * 3 + 0) * 128 + j;
    int gf = (h * 3 + 1) * 128 + j;
    int gh2 = (h * 3 + 2) * 128 + j;
    float li = (vi - mu) * r * g[gi] + beta[gi];
    float lf = (vf - mu) * r * g[gf] + beta[gf];
    float lh = (vh - mu) * r * g[gh2] + beta[gh2];
    size_t ob = (size_t)blockIdx.x * HD + t;
    fgl[ob] = f2bf(lf);
    igh[ob] = (1.f / (1.f + expf(-li))) * fmaxf(lh, 0.f);
}

// ---------------- K5a: per-chunk recurrence summary: P = prod f, L = local end value
__global__ void k5a_chunkrec(const ubf* __restrict__ fgl, const float* __restrict__ igh,
                             float* __restrict__ Pb, float* __restrict__ Lb) {
    int bid = blockIdx.x;                 // b*NC2*HH + c*HH + h
    int h = bid % HH;
    int c = (bid / HH) % NC2;
    int b = bid / (HH * NC2);
    int d = threadIdx.x;
    size_t base = (size_t)(b * SS + c * CS2) * HD + h * DOo + d;
    float P = 1.f, L = 0.f;
    for (int s = 0; s < CS2; ++s) {
        float f = 1.f / (1.f + expf(-bf2f(fgl[base + (size_t)s * HD])));
        float i = igh[base + (size_t)s * HD];
        L = f * L + i;
        P *= f;
    }
    int o = ((b * NC2 + c) * HH + h) * DOo + d;
    Pb[o] = P;
    Lb[o] = L;
}

// ---------------- K5b: serial carry across chunks
__global__ void k5b_carry(const float* __restrict__ Pb, const float* __restrict__ Lb,
                          const float* __restrict__ init_cx, float* __restrict__ cIn) {
    int bid = blockIdx.x;                 // b*HH + h
    int h = bid % HH;
    int b = bid / HH;
    int d = threadIdx.x;
    float c = init_cx[h * DOo + d];
    for (int cc = 0; cc < NC2; ++cc) {
        int o = ((b * NC2 + cc) * HH + h) * DOo + d;
        cIn[o] = c;
        c = Pb[o] * c + Lb[o];
    }
}

// ---------------- K5c: final in-chunk recurrence; cell fp32 in-place over igh (d_out) + cell bf16 copy
__global__ void k5c_cell(const ubf* __restrict__ fgl, float* __restrict__ igh_cell,
                         const float* __restrict__ cIn, ubf* __restrict__ cell_bf) {
    int bid = blockIdx.x;
    int h = bid % HH;
    int c = (bid / HH) % NC2;
    int b = bid / (HH * NC2);
    int d = threadIdx.x;
    size_t base = (size_t)(b * SS + c * CS2) * HD + h * DOo + d;
    int o = ((b * NC2 + c) * HH + h) * DOo + d;
    float cv = cIn[o];
    for (int s = 0; s < CS2; ++s) {
        float f = 1.f / (1.f + expf(-bf2f(fgl[base + (size_t)s * HD])));
        float i = igh_cell[base + (size_t)s * HD];
        cv = f * cv + i;
        igh_cell[base + (size_t)s * HD] = cv;
        cell_bf[base + (size_t)s * HD] = f2bf(cv);
    }
}

// ---------------- K6b: +bias, LN over 1024 per token, sigmoid*cell -> out (in place over cell)
__global__ void __launch_bounds__(1024) k6b_ln_out(
        const ubf* __restrict__ ogr, float* __restrict__ out /* cell in, final out */,
        const float* __restrict__ bias, const float* __restrict__ g,
        const float* __restrict__ beta) {
    __shared__ float2 scratch[16];
    size_t base = (size_t)blockIdx.x * HD;
    int t = threadIdx.x;
    float v = bf2f(ogr[base + t]) + bias[t];
    float cell = out[base + t];
    float a = v, sq = v * v;
    blockReduce2(a, sq, scratch);
    float mu  = a * (1.f / 1024.f);
    float var = sq * (1.f / 1024.f) - mu * mu;
    float r = rsqrtf(var + LNEPS);
    float og = (v - mu) * r * g[t] + beta[t];
    out[base + t] = (1.f / (1.f + expf(-og))) * cell;
}

extern "C" void kernel_launch(void* const* d_in, const int* in_sizes, int n_in,
                              void* d_out, int out_size, void* d_ws, size_t ws_size,
                              hipStream_t stream) {
    const float* heads_input = (const float*)d_in[0];
    const float* W_hid   = (const float*)d_in[1];
    const float* b_hid   = (const float*)d_in[2];
    const float* g_csum  = (const float*)d_in[3];
    const float* beta_csum = (const float*)d_in[4];
    const float* g_hid   = (const float*)d_in[5];
    const float* beta_hid = (const float*)d_in[6];
    const float* W_og    = (const float*)d_in[7];
    const float* b_og    = (const float*)d_in[8];
    const float* g_og    = (const float*)d_in[9];
    const float* beta_og = (const float*)d_in[10];
    const float* init_cx = (const float*)d_in[11];
    float* out = (float*)d_out;           // fp32 output, NTOK*HD elements

    // workspace layout (~172.5 MB)
    char* ws = (char*)d_ws;
    ubf* in_bf   = (ubf*)ws;                                   // 33,554,432 B
    ubf* csln_bf = (ubf*)(ws + (size_t)33554432);              // 33,554,432 B (later fgl)
    ubf* big     = (ubf*)(ws + (size_t)67108864);              // 100,663,296 B
    ubf* h3      = big;                                        // k4a w, k4b r
    ubf* cell_bf = big;                                        // k5c w, k6a r (h3 dead)
    ubf* og_bf   = big + (size_t)NTOK * HD;                    // k6a w, k6b r
    char* tail   = ws + (size_t)167772160;
    float* chunk = (float*)tail;                               // 1,048,576 B
    float* Pb    = chunk + (size_t)BB * NC1 * HD;              //   524,288 B
    float* Lb    = Pb + (size_t)BB * NC2 * HD;                 //   524,288 B
    float* cIn   = Lb + (size_t)BB * NC2 * HD;                 //   524,288 B
    ubf* Wt_hid  = (ubf*)(cIn + (size_t)BB * NC2 * HD);        // 1,572,864 B
    ubf* Wt_og   = Wt_hid + (size_t)HH * 384 * 256;            //   524,288 B
    ubf* fgl     = csln_bf;   // alias: csln consumed by gemm(k4a) before k4b writes fgl

    kwt<<<HH * 384, 256, 0, stream>>>(W_hid, Wt_hid, 384);
    kwt<<<HH * 128, 256, 0, stream>>>(W_og, Wt_og, 128);
    k1_chunksum<<<BB * HH * NC1, 128, 0, stream>>>(heads_input, chunk, in_bf);
    k2_chunkscan<<<BB * HH, 128, 0, stream>>>(chunk);
    k3_csum_ln<<<BB * NC1, 1024, 0, stream>>>(heads_input, chunk, g_csum, beta_csum, csln_bf);
    gemm_h<<<dim3(NTOK / 128, HH, 3), 256, 0, stream>>>(in_bf, csln_bf, Wt_hid, h3, 384);
    k4b_ln_gates<<<NTOK, 1024, 0, stream>>>(h3, b_hid, g_hid, beta_hid, fgl, out);
    k5a_chunkrec<<<BB * NC2 * HH, 128, 0, stream>>>(fgl, out, Pb, Lb);
    k5b_carry<<<BB * HH, 128, 0, stream>>>(Pb, Lb, init_cx, cIn);
    k5c_cell<<<BB * NC2 * HH, 128, 0, stream>>>(fgl, out, cIn, cell_bf);
    gemm_h<<<dim3(NTOK / 128, HH, 1), 256, 0, stream>>>(in_bf, cell_bf, Wt_og, og_bf, 128);
    k6b_ln_out<<<NTOK, 1024, 0, stream>>>(og_bf, out, b_og, g_og, beta_og);
}